// Round 4
// baseline (1196.805 us; speedup 1.0000x reference)
//
#include <hip/hip_runtime.h>
#include <hip/hip_bf16.h>
#include <math.h>

// Problem constants (PoseMixtureVAE)
#define N_BATCH 4096
#define FRAME   267
#define LATENT  32
#define HIDDEN  256
#define GATE_H  64
#define EXPERTS 6
// IN0 = LATENT + FRAME = 299, IN1 = LATENT + HIDDEN = 288, OUT = FRAME = 267

// ---------------------------------------------------------------------------
// Generic tiled GEMM:  C[n, m] = act( sum_e coeff(n,e) * ( [A1|A2][n,:] @ W_e + B_e ) )
//   A = concat(A1 [N x K1], A2 [N x K2]) row-major f32, N = 4096.
//   W: f32 [E x (K1+K2) x M] row-major. B: f32 [E x M].
//   coeff: f32 [N x EXPERTS] (nullptr => scale = 1, used with E=1).
//   act: 0 = identity, 1 = ELU(alpha=1).  Output f32.
// Tile: 64 rows x 64 cols, BK=32, 256 threads, 4x4 micro-tile per thread.
// ---------------------------------------------------------------------------
#define BM 64
#define BN 64
#define BK 32

__global__ __launch_bounds__(256) void gemm2(
    const float* __restrict__ A1, int K1,
    const float* __restrict__ A2, int K2,
    const float* __restrict__ W, const float* __restrict__ B,
    const float* __restrict__ coeff, int E,
    float* __restrict__ C, int M, int act)
{
    __shared__ float sA[BK][BM + 1];   // +1 pad: conflict-free transposed store
    __shared__ float sW[BK][BN];       // row = k, 16B-aligned float4 reads

    const int tid  = threadIdx.x;
    const int tx   = tid & 15;         // col group: cols tx*4 .. tx*4+3
    const int ty   = tid >> 4;         // row group: rows ty, ty+16, ty+32, ty+48
    const int row0 = blockIdx.y * BM;
    const int col0 = blockIdx.x * BN;
    const int Kt   = K1 + K2;

    float acc[4][4] = {{0.f, 0.f, 0.f, 0.f}};

    for (int e = 0; e < E; ++e) {
        float acce[4][4] = {{0.f, 0.f, 0.f, 0.f}};
        const float* We = W + (size_t)e * Kt * M;

        for (int k0 = 0; k0 < Kt; k0 += BK) {
            // stage A tile [BM x BK] transposed into sA[k][row]
            {
                const int kk = tid & 31;
                const int gk = k0 + kk;
                const int r0 = tid >> 5;           // 0..7
                #pragma unroll
                for (int it = 0; it < BM / 8; ++it) {
                    const int rr = r0 + it * 8;
                    float v = 0.f;
                    if (gk < Kt) {
                        const int gr = row0 + rr;
                        v = (gk < K1) ? A1[(size_t)gr * K1 + gk]
                                      : A2[(size_t)gr * K2 + (gk - K1)];
                    }
                    sA[kk][rr] = v;
                }
            }
            // stage W tile [BK x BN]
            {
                const int cc = tid & 63;
                const int gc = col0 + cc;
                const int kb = tid >> 6;           // 0..3
                #pragma unroll
                for (int it = 0; it < BK / 4; ++it) {
                    const int kk = kb + it * 4;
                    const int gk = k0 + kk;
                    float v = 0.f;
                    if (gk < Kt && gc < M) v = We[(size_t)gk * M + gc];
                    sW[kk][cc] = v;
                }
            }
            __syncthreads();

            #pragma unroll
            for (int kk = 0; kk < BK; ++kk) {
                const float a0 = sA[kk][ty];
                const float a1 = sA[kk][ty + 16];
                const float a2 = sA[kk][ty + 32];
                const float a3 = sA[kk][ty + 48];
                const float4 w = *(const float4*)(&sW[kk][tx * 4]);
                acce[0][0] += a0 * w.x; acce[0][1] += a0 * w.y; acce[0][2] += a0 * w.z; acce[0][3] += a0 * w.w;
                acce[1][0] += a1 * w.x; acce[1][1] += a1 * w.y; acce[1][2] += a1 * w.z; acce[1][3] += a1 * w.w;
                acce[2][0] += a2 * w.x; acce[2][1] += a2 * w.y; acce[2][2] += a2 * w.z; acce[2][3] += a2 * w.w;
                acce[3][0] += a3 * w.x; acce[3][1] += a3 * w.y; acce[3][2] += a3 * w.z; acce[3][3] += a3 * w.w;
            }
            __syncthreads();
        }

        // blend expert e: acc += coeff[n,e] * (acce + bias_e)
        #pragma unroll
        for (int r = 0; r < 4; ++r) {
            const int gr = row0 + ty + 16 * r;
            const float s = coeff ? coeff[(size_t)gr * EXPERTS + e] : 1.f;
            #pragma unroll
            for (int j = 0; j < 4; ++j) {
                const int gc = col0 + tx * 4 + j;
                const float b = (gc < M) ? B[(size_t)e * M + gc] : 0.f;
                acc[r][j] += s * (acce[r][j] + b);
            }
        }
    }

    // activation + store (f32)
    #pragma unroll
    for (int r = 0; r < 4; ++r) {
        const int gr = row0 + ty + 16 * r;
        #pragma unroll
        for (int j = 0; j < 4; ++j) {
            const int gc = col0 + tx * 4 + j;
            if (gc < M) {
                float v = acc[r][j];
                if (act) v = (v > 0.f) ? v : (expf(v) - 1.f);
                C[(size_t)gr * M + gc] = v;
            }
        }
    }
}

// ---------------------------------------------------------------------------
// z = mu + eps * exp(0.5 * logvar).  mu/lv were written directly to d_out.
// ---------------------------------------------------------------------------
__global__ void z_kernel(const float* __restrict__ mu, const float* __restrict__ lv,
                         const float* __restrict__ eps, float* __restrict__ z) {
    int i = blockIdx.x * blockDim.x + threadIdx.x;
    if (i >= N_BATCH * LATENT) return;
    z[i] = mu[i] + eps[i] * expf(0.5f * lv[i]);
}

// ---------------------------------------------------------------------------
// In-place softmax over EXPERTS=6 logits per row.
// ---------------------------------------------------------------------------
__global__ void softmax_kernel(float* __restrict__ co) {
    int n = blockIdx.x * blockDim.x + threadIdx.x;
    if (n >= N_BATCH) return;
    float v[EXPERTS];
    float m = -1e30f;
    #pragma unroll
    for (int i = 0; i < EXPERTS; ++i) { v[i] = co[(size_t)n * EXPERTS + i]; m = fmaxf(m, v[i]); }
    float s = 0.f;
    #pragma unroll
    for (int i = 0; i < EXPERTS; ++i) { v[i] = expf(v[i] - m); s += v[i]; }
    const float inv = 1.f / s;
    #pragma unroll
    for (int i = 0; i < EXPERTS; ++i) co[(size_t)n * EXPERTS + i] = v[i] * inv;
}

// ---------------------------------------------------------------------------
extern "C" void kernel_launch(void* const* d_in, const int* in_sizes, int n_in,
                              void* d_out, int out_size, void* d_ws, size_t ws_size,
                              hipStream_t stream) {
    // inputs (all float32, setup_inputs() order)
    const float* x       = (const float*)d_in[0];
    const float* c       = (const float*)d_in[1];
    const float* eps     = (const float*)d_in[2];
    const float* enc_w1  = (const float*)d_in[3];
    const float* enc_b1  = (const float*)d_in[4];
    const float* enc_w2  = (const float*)d_in[5];
    const float* enc_b2  = (const float*)d_in[6];
    const float* enc_wmu = (const float*)d_in[7];
    const float* enc_bmu = (const float*)d_in[8];
    const float* enc_wlv = (const float*)d_in[9];
    const float* enc_blv = (const float*)d_in[10];
    const float* g_w0    = (const float*)d_in[11];
    const float* g_b0    = (const float*)d_in[12];
    const float* g_w1    = (const float*)d_in[13];
    const float* g_b1    = (const float*)d_in[14];
    const float* g_w2    = (const float*)d_in[15];
    const float* g_b2    = (const float*)d_in[16];
    const float* w0      = (const float*)d_in[17];
    const float* b0      = (const float*)d_in[18];
    const float* w1      = (const float*)d_in[19];
    const float* b1      = (const float*)d_in[20];
    const float* w2      = (const float*)d_in[21];
    const float* b2      = (const float*)d_in[22];

    // output (f32): [layer (4096x267) | mu (4096x32) | logvar (4096x32)]
    float* out_layer = (float*)d_out;
    float* out_mu    = out_layer + (size_t)N_BATCH * FRAME;
    float* out_lv    = out_mu    + (size_t)N_BATCH * LATENT;

    // f32 workspace (non-aliased, ~18.6 MB)
    float* ws  = (float*)d_ws;
    float* h1  = ws;                                   // 4096*256
    float* h2  = h1  + (size_t)N_BATCH * HIDDEN;       // 4096*256
    float* z   = h2  + (size_t)N_BATCH * HIDDEN;       // 4096*32
    float* g1  = z   + (size_t)N_BATCH * LATENT;       // 4096*64
    float* g2  = g1  + (size_t)N_BATCH * GATE_H;       // 4096*64
    float* co  = g2  + (size_t)N_BATCH * GATE_H;       // 4096*6
    float* dh1 = co  + (size_t)N_BATCH * EXPERTS;      // 4096*256
    float* dh2 = dh1 + (size_t)N_BATCH * HIDDEN;       // 4096*256

    const dim3 blk(256);
    const int gy = N_BATCH / BM;   // 64 row-tiles

    // 1) h1 = elu([x|c] @ enc_w1 + b1)            K=534, M=256
    gemm2<<<dim3(HIDDEN / BN, gy), blk, 0, stream>>>(x, FRAME, c, FRAME,
        enc_w1, enc_b1, nullptr, 1, h1, HIDDEN, 1);

    // 2) h2 = elu([x|h1] @ enc_w2 + b2)           K=523, M=256
    gemm2<<<dim3(HIDDEN / BN, gy), blk, 0, stream>>>(x, FRAME, h1, HIDDEN,
        enc_w2, enc_b2, nullptr, 1, h2, HIDDEN, 1);

    // 3) mu = [x|h2] @ enc_wmu + bmu  -> d_out    K=523, M=32
    gemm2<<<dim3(1, gy), blk, 0, stream>>>(x, FRAME, h2, HIDDEN,
        enc_wmu, enc_bmu, nullptr, 1, out_mu, LATENT, 0);

    // 4) logvar = [x|h2] @ enc_wlv + blv -> d_out
    gemm2<<<dim3(1, gy), blk, 0, stream>>>(x, FRAME, h2, HIDDEN,
        enc_wlv, enc_blv, nullptr, 1, out_lv, LATENT, 0);

    // 5) z = mu + eps * exp(0.5*logvar)
    z_kernel<<<dim3((N_BATCH * LATENT + 255) / 256), blk, 0, stream>>>(out_mu, out_lv, eps, z);

    // 6) g1 = elu([z|c] @ g_w0 + b0)              K=299, M=64
    gemm2<<<dim3(1, gy), blk, 0, stream>>>(z, LATENT, c, FRAME,
        g_w0, g_b0, nullptr, 1, g1, GATE_H, 1);

    // 7) g2 = elu(g1 @ g_w1 + b1)                 K=64, M=64
    gemm2<<<dim3(1, gy), blk, 0, stream>>>(g1, GATE_H, g1, 0,
        g_w1, g_b1, nullptr, 1, g2, GATE_H, 1);

    // 8) logits = g2 @ g_w2 + b2                  K=64, M=6
    gemm2<<<dim3(1, gy), blk, 0, stream>>>(g2, GATE_H, g2, 0,
        g_w2, g_b2, nullptr, 1, co, EXPERTS, 0);

    // 9) coeff = softmax(logits)
    softmax_kernel<<<dim3((N_BATCH + 255) / 256), blk, 0, stream>>>(co);

    // 10) dh1 = elu(moe([z|c], w0, b0))           K=299, M=256
    gemm2<<<dim3(HIDDEN / BN, gy), blk, 0, stream>>>(z, LATENT, c, FRAME,
        w0, b0, co, EXPERTS, dh1, HIDDEN, 1);

    // 11) dh2 = elu(moe([z|dh1], w1, b1))         K=288, M=256
    gemm2<<<dim3(HIDDEN / BN, gy), blk, 0, stream>>>(z, LATENT, dh1, HIDDEN,
        w1, b1, co, EXPERTS, dh2, HIDDEN, 1);

    // 12) out = moe([z|dh2], w2, b2) -> d_out     K=288, M=267
    gemm2<<<dim3((FRAME + BN - 1) / BN, gy), blk, 0, stream>>>(z, LATENT, dh2, HIDDEN,
        w2, b2, co, EXPERTS, out_layer, FRAME, 0);
}

// Round 5
// 310.453 us; speedup vs baseline: 3.8550x; 3.8550x over previous
//
#include <hip/hip_runtime.h>
#include <hip/hip_bf16.h>
#include <math.h>

// Problem constants (PoseMixtureVAE)
#define N_BATCH 4096
#define FRAME   267
#define LATENT  32
#define HIDDEN  256
#define GATE_H  64
#define EXPERTS 6
// concat K's: [x|c]=534->pad544, [x|h]=523->pad544, [z|c]=299->pad320, [z|h]=288 (exact)

typedef __hip_bfloat16 bf16;
typedef __bf16  bf16x8 __attribute__((ext_vector_type(8)));
typedef float   f32x4  __attribute__((ext_vector_type(4)));

// ---------------------------------------------------------------------------
// Build bf16 concat-activation buffers from f32 inputs:
//   Axc  [4096][544] = [x | c | 0]
//   Axh1 [4096][544] = [x | (h1 by gemm epi) | 0-tail]
//   Axh2 [4096][544] = [x | (h2 by gemm epi) | 0-tail]
//   Azc  [4096][320] = [(z by z_kernel) | c | 0]
// ---------------------------------------------------------------------------
__global__ void cvt_kernel(const float* __restrict__ x, const float* __restrict__ c,
                           bf16* __restrict__ Axc, bf16* __restrict__ Axh1,
                           bf16* __restrict__ Axh2, bf16* __restrict__ Azc) {
    const int col = blockIdx.x * blockDim.x + threadIdx.x;
    const int r   = blockIdx.y;
    if (col >= 544) return;
    const size_t o = (size_t)r * 544 + col;
    // Axc
    float vx = 0.f;
    if (col < FRAME)          vx = x[(size_t)r * FRAME + col];
    else if (col < 2 * FRAME) vx = c[(size_t)r * FRAME + col - FRAME];
    Axc[o] = __float2bfloat16(vx);
    // Axh1/Axh2: x part + zero tail (cols 523..543); middle filled by epilogues
    if (col < FRAME) {
        bf16 v = __float2bfloat16(x[(size_t)r * FRAME + col]);
        Axh1[o] = v; Axh2[o] = v;
    } else if (col >= FRAME + HIDDEN) {
        bf16 zv = __float2bfloat16(0.f);
        Axh1[o] = zv; Axh2[o] = zv;
    }
    // Azc: cols 32..298 = c, 299..319 = 0; cols 0..31 by z_kernel
    if (col >= 32 && col < 320) {
        float vc = (col < 32 + FRAME) ? c[(size_t)r * FRAME + col - 32] : 0.f;
        Azc[(size_t)r * 320 + col] = __float2bfloat16(vc);
    }
}

// ---------------------------------------------------------------------------
// Weight transpose + cast: W f32 [E][K][M] -> Wt bf16 [E][M][Kpad], zero-pad K.
// 32x32 LDS tile, 256 threads. grid (Kpad/32, ceil(M/32), E).
// ---------------------------------------------------------------------------
__global__ void wtr_kernel(const float* __restrict__ W, bf16* __restrict__ Wt,
                           int K, int M, int Kpad) {
    __shared__ float t[32][33];
    const int e  = blockIdx.z;
    const int k0 = blockIdx.x * 32, m0 = blockIdx.y * 32;
    const int tx = threadIdx.x & 31, ty = threadIdx.x >> 5;   // 0..31, 0..7
    const float* We = W + (size_t)e * K * M;
    bf16* Wte = Wt + (size_t)e * M * Kpad;
    #pragma unroll
    for (int i0 = 0; i0 < 32; i0 += 8) {
        const int k = k0 + i0 + ty, m = m0 + tx;
        t[i0 + ty][tx] = (k < K && m < M) ? We[(size_t)k * M + m] : 0.f;
    }
    __syncthreads();
    #pragma unroll
    for (int i0 = 0; i0 < 32; i0 += 8) {
        const int m = m0 + i0 + ty, k = k0 + tx;
        if (m < M) Wte[(size_t)m * Kpad + k] = __float2bfloat16(t[tx][i0 + ty]);
    }
}

// ---------------------------------------------------------------------------
// MFMA GEMM:  C[n,m] = act( sum_e coeff[n,e] * (A[n,:] @ We + bias_e) )
//   A  : bf16 [4096][lda], lda % 32 == 0, zero-padded K (lda == Kpad).
//   Wt : bf16 [E][M][lda]  (transposed weights, contiguous K per output col).
//   bias f32 [E][M]; coeff f32 [4096][6] or nullptr (=> scale 1).
//   Out: f32 Cf (ldc) and/or bf16 Cb (ldcb, pre-offset for concat buffers).
// Tile 64x64, 256 threads = 4 waves; wave w owns cols [16w,16w+16).
// v_mfma_f32_16x16x32_bf16 layouts (HW-verified, learn_hip m89/m91/m120):
//   A-frag: m=lane&15, k=quad*8+j ; B-frag: n=lane&15, k=quad*8+j
//   D: col=lane&15, row=quad*4+reg
// ---------------------------------------------------------------------------
#define LDST 40   // LDS row stride (bf16 elems): 80B breaks b128 bank conflicts

__global__ __launch_bounds__(256) void gemm_mfma(
    const bf16* __restrict__ A, int lda,
    const bf16* __restrict__ Wt,
    const float* __restrict__ bias,
    const float* __restrict__ coeff, int E, int M,
    float* __restrict__ Cf, int ldc,
    bf16* __restrict__ Cb, int ldcb,
    int act)
{
    __shared__ bf16 sA[64 * LDST];
    __shared__ bf16 sB[64 * LDST];
    __shared__ float sCo[64][EXPERTS];

    const int tid  = threadIdx.x;
    const int row0 = blockIdx.y * 64;
    const int col0 = blockIdx.x * 64;
    const int w    = tid >> 6;          // wave 0..3
    const int lane = tid & 63;
    const int ml   = lane & 15;
    const int quad = lane >> 4;
    const int Ksteps = lda / 32;

    // per-row blend coefficients -> LDS (1.0 when coeff == nullptr)
    for (int idx = tid; idx < 64 * EXPERTS; idx += 256) {
        const int r = idx / EXPERTS, e = idx % EXPERTS;
        sCo[r][e] = coeff ? coeff[(size_t)(row0 + r) * EXPERTS + e] : 1.f;
    }

    const int sr = tid >> 2;            // staging row 0..63
    const int sc = (tid & 3) * 8;       // staging k-chunk 0/8/16/24

    const int gcol = col0 + 16 * w + ml;

    f32x4 acc[4];
    #pragma unroll
    for (int rt = 0; rt < 4; ++rt) acc[rt] = (f32x4){0.f, 0.f, 0.f, 0.f};

    for (int e = 0; e < E; ++e) {
        f32x4 acce[4];
        #pragma unroll
        for (int rt = 0; rt < 4; ++rt) acce[rt] = (f32x4){0.f, 0.f, 0.f, 0.f};
        const bf16* We = Wt + (size_t)e * M * lda;

        for (int ks = 0; ks < Ksteps; ++ks) {
            const int k0 = ks * 32;
            // stage A tile [64 rows x 32 k] (16B per thread)
            const float4 av = *(const float4*)(A + (size_t)(row0 + sr) * lda + k0 + sc);
            // stage B tile [64 cols x 32 k]
            float4 bv = make_float4(0.f, 0.f, 0.f, 0.f);
            if (col0 + sr < M)
                bv = *(const float4*)(We + (size_t)(col0 + sr) * lda + k0 + sc);
            __syncthreads();   // also covers sCo on first iteration
            *(float4*)(sA + sr * LDST + sc) = av;
            *(float4*)(sB + sr * LDST + sc) = bv;
            __syncthreads();

            const bf16x8 bfr = *(const bf16x8*)(sB + (16 * w + ml) * LDST + 8 * quad);
            #pragma unroll
            for (int rt = 0; rt < 4; ++rt) {
                const bf16x8 afr = *(const bf16x8*)(sA + (16 * rt + ml) * LDST + 8 * quad);
                acce[rt] = __builtin_amdgcn_mfma_f32_16x16x32_bf16(afr, bfr, acce[rt], 0, 0, 0);
            }
        }

        const float bv = (gcol < M) ? bias[(size_t)e * M + gcol] : 0.f;
        #pragma unroll
        for (int rt = 0; rt < 4; ++rt)
            #pragma unroll
            for (int rg = 0; rg < 4; ++rg) {
                const float s = sCo[16 * rt + 4 * quad + rg][e];
                acc[rt][rg] += s * (acce[rt][rg] + bv);
            }
        __syncthreads();   // protect sA/sB reuse across experts
    }

    if (gcol < M) {
        #pragma unroll
        for (int rt = 0; rt < 4; ++rt)
            #pragma unroll
            for (int rg = 0; rg < 4; ++rg) {
                const int gr = row0 + 16 * rt + 4 * quad + rg;
                float v = acc[rt][rg];
                if (act) v = (v > 0.f) ? v : (expf(v) - 1.f);
                if (Cf) Cf[(size_t)gr * ldc + gcol] = v;
                if (Cb) Cb[(size_t)gr * ldcb + gcol] = __float2bfloat16(v);
            }
    }
}

// ---------------------------------------------------------------------------
// z = mu + eps*exp(0.5*lv) (mu/lv already in d_out, f32). Write z as bf16 into
// the three concat buffers' [0,32) columns.
// ---------------------------------------------------------------------------
__global__ void z_kernel(const float* __restrict__ mu, const float* __restrict__ lv,
                         const float* __restrict__ eps,
                         bf16* __restrict__ Azc, bf16* __restrict__ Azd1,
                         bf16* __restrict__ Azd2) {
    const int i = blockIdx.x * blockDim.x + threadIdx.x;
    if (i >= N_BATCH * LATENT) return;
    const int r = i >> 5, cidx = i & 31;
    const float zv = mu[i] + eps[i] * expf(0.5f * lv[i]);
    const bf16 v = __float2bfloat16(zv);
    Azc [(size_t)r * 320 + cidx] = v;
    Azd1[(size_t)r * 288 + cidx] = v;
    Azd2[(size_t)r * 288 + cidx] = v;
}

// ---------------------------------------------------------------------------
// In-place softmax over EXPERTS=6 logits per row (f32).
// ---------------------------------------------------------------------------
__global__ void softmax_kernel(float* __restrict__ co) {
    const int n = blockIdx.x * blockDim.x + threadIdx.x;
    if (n >= N_BATCH) return;
    float v[EXPERTS];
    float m = -1e30f;
    #pragma unroll
    for (int i = 0; i < EXPERTS; ++i) { v[i] = co[(size_t)n * EXPERTS + i]; m = fmaxf(m, v[i]); }
    float s = 0.f;
    #pragma unroll
    for (int i = 0; i < EXPERTS; ++i) { v[i] = expf(v[i] - m); s += v[i]; }
    const float inv = 1.f / s;
    #pragma unroll
    for (int i = 0; i < EXPERTS; ++i) co[(size_t)n * EXPERTS + i] = v[i] * inv;
}

// ---------------------------------------------------------------------------
extern "C" void kernel_launch(void* const* d_in, const int* in_sizes, int n_in,
                              void* d_out, int out_size, void* d_ws, size_t ws_size,
                              hipStream_t stream) {
    const float* x       = (const float*)d_in[0];
    const float* c       = (const float*)d_in[1];
    const float* eps     = (const float*)d_in[2];
    const float* enc_w1  = (const float*)d_in[3];
    const float* enc_b1  = (const float*)d_in[4];
    const float* enc_w2  = (const float*)d_in[5];
    const float* enc_b2  = (const float*)d_in[6];
    const float* enc_wmu = (const float*)d_in[7];
    const float* enc_bmu = (const float*)d_in[8];
    const float* enc_wlv = (const float*)d_in[9];
    const float* enc_blv = (const float*)d_in[10];
    const float* g_w0    = (const float*)d_in[11];
    const float* g_b0    = (const float*)d_in[12];
    const float* g_w1    = (const float*)d_in[13];
    const float* g_b1    = (const float*)d_in[14];
    const float* g_w2    = (const float*)d_in[15];
    const float* g_b2    = (const float*)d_in[16];
    const float* w0      = (const float*)d_in[17];
    const float* b0      = (const float*)d_in[18];
    const float* w1      = (const float*)d_in[19];
    const float* b1      = (const float*)d_in[20];
    const float* w2      = (const float*)d_in[21];
    const float* b2      = (const float*)d_in[22];

    // output (f32): [layer (4096x267) | mu (4096x32) | logvar (4096x32)]
    float* out_layer = (float*)d_out;
    float* out_mu    = out_layer + (size_t)N_BATCH * FRAME;
    float* out_lv    = out_mu    + (size_t)N_BATCH * LATENT;

    // ---- workspace layout (bytes; all 16B-aligned) ----
    char* p = (char*)d_ws;
    float* co = (float*)p;            p += (size_t)N_BATCH * EXPERTS * 4;     // 98304
    bf16* Axc   = (bf16*)p;           p += (size_t)N_BATCH * 544 * 2;
    bf16* Axh1  = (bf16*)p;           p += (size_t)N_BATCH * 544 * 2;
    bf16* Axh2  = (bf16*)p;           p += (size_t)N_BATCH * 544 * 2;
    bf16* Azc   = (bf16*)p;           p += (size_t)N_BATCH * 320 * 2;
    bf16* Azd1  = (bf16*)p;           p += (size_t)N_BATCH * 288 * 2;
    bf16* Azd2  = (bf16*)p;           p += (size_t)N_BATCH * 288 * 2;
    bf16* Bg1   = (bf16*)p;           p += (size_t)N_BATCH * 64 * 2;
    bf16* Bg2   = (bf16*)p;           p += (size_t)N_BATCH * 64 * 2;
    bf16* Wt_e1 = (bf16*)p;           p += (size_t)256 * 544 * 2;
    bf16* Wt_e2 = (bf16*)p;           p += (size_t)256 * 544 * 2;
    bf16* Wt_mu = (bf16*)p;           p += (size_t)32 * 544 * 2;
    bf16* Wt_lv = (bf16*)p;           p += (size_t)32 * 544 * 2;
    bf16* Wt_g0 = (bf16*)p;           p += (size_t)64 * 320 * 2;
    bf16* Wt_g1 = (bf16*)p;           p += (size_t)64 * 64 * 2;
    bf16* Wt_g2 = (bf16*)p;           p += (size_t)6 * 64 * 2 + 256;          // pad
    bf16* Wt_w0 = (bf16*)p;           p += (size_t)EXPERTS * 256 * 320 * 2;
    bf16* Wt_w1 = (bf16*)p;           p += (size_t)EXPERTS * 256 * 288 * 2;
    bf16* Wt_w2 = (bf16*)p;           p += (size_t)EXPERTS * 267 * 288 * 2;
    // total ~25.1 MB

    const dim3 blk(256);

    // ---- stage 0: conversions (independent of each other) ----
    cvt_kernel<<<dim3(3, N_BATCH), blk, 0, stream>>>(x, c, Axc, Axh1, Axh2, Azc);
    wtr_kernel<<<dim3(17, 8, 1), blk, 0, stream>>>(enc_w1,  Wt_e1, 534, 256, 544);
    wtr_kernel<<<dim3(17, 8, 1), blk, 0, stream>>>(enc_w2,  Wt_e2, 523, 256, 544);
    wtr_kernel<<<dim3(17, 1, 1), blk, 0, stream>>>(enc_wmu, Wt_mu, 523, 32, 544);
    wtr_kernel<<<dim3(17, 1, 1), blk, 0, stream>>>(enc_wlv, Wt_lv, 523, 32, 544);
    wtr_kernel<<<dim3(10, 2, 1), blk, 0, stream>>>(g_w0,    Wt_g0, 299, 64, 320);
    wtr_kernel<<<dim3(2, 2, 1),  blk, 0, stream>>>(g_w1,    Wt_g1, 64, 64, 64);
    wtr_kernel<<<dim3(2, 1, 1),  blk, 0, stream>>>(g_w2,    Wt_g2, 64, 6, 64);
    wtr_kernel<<<dim3(10, 8, EXPERTS), blk, 0, stream>>>(w0, Wt_w0, 299, 256, 320);
    wtr_kernel<<<dim3(9, 8, EXPERTS),  blk, 0, stream>>>(w1, Wt_w1, 288, 256, 288);
    wtr_kernel<<<dim3(9, 9, EXPERTS),  blk, 0, stream>>>(w2, Wt_w2, 288, 267, 288);

    const int gy = N_BATCH / 64;   // 64 row-tiles

    // 1) h1 = elu([x|c] @ enc_w1 + b1) -> Axh1[:,267:523]
    gemm_mfma<<<dim3(4, gy), blk, 0, stream>>>(Axc, 544, Wt_e1, enc_b1,
        nullptr, 1, 256, nullptr, 0, Axh1 + FRAME, 544, 1);
    // 2) h2 = elu([x|h1] @ enc_w2 + b2) -> Axh2[:,267:523]
    gemm_mfma<<<dim3(4, gy), blk, 0, stream>>>(Axh1, 544, Wt_e2, enc_b2,
        nullptr, 1, 256, nullptr, 0, Axh2 + FRAME, 544, 1);
    // 3) mu -> d_out (f32)
    gemm_mfma<<<dim3(1, gy), blk, 0, stream>>>(Axh2, 544, Wt_mu, enc_bmu,
        nullptr, 1, 32, out_mu, 32, nullptr, 0, 0);
    // 4) logvar -> d_out (f32)
    gemm_mfma<<<dim3(1, gy), blk, 0, stream>>>(Axh2, 544, Wt_lv, enc_blv,
        nullptr, 1, 32, out_lv, 32, nullptr, 0, 0);
    // 5) z -> [0,32) cols of Azc/Azd1/Azd2 (bf16)
    z_kernel<<<dim3((N_BATCH * LATENT + 255) / 256), blk, 0, stream>>>(
        out_mu, out_lv, eps, Azc, Azd1, Azd2);
    // 6) g1 = elu([z|c] @ g_w0 + b0) -> Bg1
    gemm_mfma<<<dim3(1, gy), blk, 0, stream>>>(Azc, 320, Wt_g0, g_b0,
        nullptr, 1, 64, nullptr, 0, Bg1, 64, 1);
    // 7) g2 = elu(g1 @ g_w1 + b1) -> Bg2
    gemm_mfma<<<dim3(1, gy), blk, 0, stream>>>(Bg1, 64, Wt_g1, g_b1,
        nullptr, 1, 64, nullptr, 0, Bg2, 64, 1);
    // 8) logits = g2 @ g_w2 + b2 -> co (f32)
    gemm_mfma<<<dim3(1, gy), blk, 0, stream>>>(Bg2, 64, Wt_g2, g_b2,
        nullptr, 1, EXPERTS, co, EXPERTS, nullptr, 0, 0);
    // 9) coeff = softmax(logits)
    softmax_kernel<<<dim3((N_BATCH + 255) / 256), blk, 0, stream>>>(co);
    // 10) dh1 = elu(moe([z|c], w0, b0)) -> Azd1[:,32:288]
    gemm_mfma<<<dim3(4, gy), blk, 0, stream>>>(Azc, 320, Wt_w0, b0,
        co, EXPERTS, 256, nullptr, 0, Azd1 + LATENT, 288, 1);
    // 11) dh2 = elu(moe([z|dh1], w1, b1)) -> Azd2[:,32:288]
    gemm_mfma<<<dim3(4, gy), blk, 0, stream>>>(Azd1, 288, Wt_w1, b1,
        co, EXPERTS, 256, nullptr, 0, Azd2 + LATENT, 288, 1);
    // 12) out = moe([z|dh2], w2, b2) -> d_out (f32)
    gemm_mfma<<<dim3(5, gy), blk, 0, stream>>>(Azd2, 288, Wt_w2, b2,
        co, EXPERTS, FRAME, out_layer, FRAME, nullptr, 0, 0);
}

// Round 6
// 263.854 us; speedup vs baseline: 4.5359x; 1.1766x over previous
//
#include <hip/hip_runtime.h>
#include <hip/hip_bf16.h>
#include <math.h>

// Problem constants (PoseMixtureVAE)
#define N_BATCH 4096
#define FRAME   267
#define LATENT  32
#define HIDDEN  256
#define GATE_H  64
#define EXPERTS 6
// Kpads: [x|c]=534->544, [x|h]=523->544, [z|c]=299->320, [z|h]=288, gate=64

typedef __hip_bfloat16 bf16;
typedef __bf16  bf16x8 __attribute__((ext_vector_type(8)));
typedef float   f32x4  __attribute__((ext_vector_type(4)));

__device__ __forceinline__ void async_ld16(const void* g, void* l) {
    __builtin_amdgcn_global_load_lds(
        (const __attribute__((address_space(1))) unsigned int*)g,
        (__attribute__((address_space(3))) unsigned int*)l, 16, 0, 0);
}

// ---------------------------------------------------------------------------
// cvt: build bf16 concat-activation buffers + concat bias for mu|lv GEMM.
//   Axc [4096][544] = [x | c | 0];  Axh1/Axh2 [4096][544]: x part + zero tail
//   Azc [4096][320]: cols 32..298 = c, 299..319 = 0 (cols 0..31 by z_kernel)
//   biasCat[64] = [enc_bmu | enc_blv]
// ---------------------------------------------------------------------------
__global__ void cvt_kernel(const float* __restrict__ x, const float* __restrict__ c,
                           const float* __restrict__ bmu, const float* __restrict__ blv,
                           bf16* __restrict__ Axc, bf16* __restrict__ Axh1,
                           bf16* __restrict__ Axh2, bf16* __restrict__ Azc,
                           float* __restrict__ biasCat) {
    const int col = blockIdx.x * blockDim.x + threadIdx.x;
    const int r   = blockIdx.y;
    if (blockIdx.x == 0 && r == 0 && threadIdx.x < 64)
        biasCat[threadIdx.x] = (threadIdx.x < 32) ? bmu[threadIdx.x] : blv[threadIdx.x - 32];
    if (col >= 544) return;
    const size_t o = (size_t)r * 544 + col;
    float vx = 0.f;
    if (col < FRAME)          vx = x[(size_t)r * FRAME + col];
    else if (col < 2 * FRAME) vx = c[(size_t)r * FRAME + col - FRAME];
    Axc[o] = __float2bfloat16(vx);
    if (col < FRAME) {
        bf16 v = __float2bfloat16(x[(size_t)r * FRAME + col]);
        Axh1[o] = v; Axh2[o] = v;
    } else if (col >= FRAME + HIDDEN) {
        bf16 zv = __float2bfloat16(0.f);
        Axh1[o] = zv; Axh2[o] = zv;
    }
    if (col >= 32 && col < 320) {
        float vc = (col < 32 + FRAME) ? c[(size_t)r * FRAME + col - 32] : 0.f;
        Azc[(size_t)r * 320 + col] = __float2bfloat16(vc);
    }
}

// ---------------------------------------------------------------------------
// Fused weight repack: src f32 [E][K][M] -> dst bf16 [E][Ksteps][Mtot][32],
// i.e. k-block-contiguous: dst[((e*Ksteps+ks)*Mtot + mOff+m)*32 + kin].
// Zero-pad k>=K and m in [M, Mtiles*32). One launch for all 10 tensors.
// ---------------------------------------------------------------------------
struct WEnt { const float* src; bf16* dst; int K, M, Mtot, mOff, Ksteps, Mtiles, cum; };
struct WTab { WEnt e[10]; int total; };

__global__ __launch_bounds__(256) void wtr_kernel(WTab tab) {
    __shared__ float tbuf[32][33];
    const int bid = blockIdx.x;
    int i = 0;
    while (i < 9 && bid >= tab.e[i + 1].cum) ++i;
    const WEnt en = tab.e[i];
    const int t    = bid - en.cum;
    const int perE = en.Ksteps * en.Mtiles;
    const int e    = t / perE;
    const int r    = t - e * perE;
    const int mt   = r / en.Ksteps;
    const int ks   = r - mt * en.Ksteps;

    const int tx = threadIdx.x & 31, ty = threadIdx.x >> 5;   // 0..31, 0..7
    const float* src = en.src + (size_t)e * en.K * en.M;
    #pragma unroll
    for (int i0 = 0; i0 < 32; i0 += 8) {
        const int k = ks * 32 + i0 + ty, m = mt * 32 + tx;
        tbuf[i0 + ty][tx] = (k < en.K && m < en.M) ? src[(size_t)k * en.M + m] : 0.f;
    }
    __syncthreads();
    bf16* dst = en.dst + ((size_t)(e * en.Ksteps + ks) * en.Mtot + en.mOff + mt * 32) * 32;
    #pragma unroll
    for (int i0 = 0; i0 < 32; i0 += 8) {
        const int mm = i0 + ty;            // local m row, kin = tx
        dst[(size_t)mm * 32 + tx] = __float2bfloat16(tbuf[tx][mm]);
    }
}

// ---------------------------------------------------------------------------
// MFMA GEMM:  C[n,m] = act( sum_e coeff[n,e] * (A[n,:] @ We + bias_e) )
//   A: bf16 [4096][Kpad] (Kpad%32==0, zero-padded). Wt: [E][Ksteps][Mtot][32].
//   bias f32 [E][M]; coeff f32 [4096][6] or nullptr.
//   Tile 32 rows x 64 cols, 256 thr = 4 waves (wave w: cols 16w..16w+15).
//   Full-K A staged once in LDS; B staged per (e,ks) via global_load_lds x16.
//   Dyn LDS: 32*(Kpad+8)*2 (sA) + 4096 (sB) + 768 (sCo).
// ---------------------------------------------------------------------------
__global__ __launch_bounds__(256) void gemm_moe(
    const bf16* __restrict__ A, int Kpad,
    const bf16* __restrict__ Wt,
    const float* __restrict__ bias,
    const float* __restrict__ coeff, int E, int M, int Mtot,
    float* __restrict__ Cf, int ldc,
    bf16* __restrict__ Cb, int ldcb, int act)
{
    extern __shared__ char smem[];
    const int strideA = Kpad + 8;      // (Kpad+8)*2 bytes stays 16B-aligned
    bf16*  sA  = (bf16*)smem;
    bf16*  sB  = (bf16*)(smem + (size_t)32 * strideA * 2);
    float* sCo = (float*)(smem + (size_t)32 * strideA * 2 + 4096);

    const int tid  = threadIdx.x;
    const int w    = tid >> 6, lane = tid & 63;
    const int ml   = lane & 15, quad = lane >> 4;
    const int row0 = blockIdx.y * 32;
    const int col0 = blockIdx.x * 64;
    const int Ksteps = Kpad >> 5;

    if (tid < 32 * EXPERTS) {
        const int e = tid >> 5, r = tid & 31;
        sCo[e * 32 + r] = coeff ? coeff[(size_t)(row0 + r) * EXPERTS + e] : 1.f;
    }
    {   // full-K A tile: 32 rows x Kpad, 8 threads/row x 16B chunks
        const int r = tid >> 3, kt = (tid & 7) * 8;
        for (int kk = kt; kk < Kpad; kk += 64) {
            const float4 v = *(const float4*)(A + (size_t)(row0 + r) * Kpad + kk);
            *(float4*)(sA + r * strideA + kk) = v;
        }
    }

    const int gcol = col0 + 16 * w + ml;
    f32x4 acc[2];
    acc[0] = (f32x4){0.f, 0.f, 0.f, 0.f};
    acc[1] = (f32x4){0.f, 0.f, 0.f, 0.f};

    bf16* sBw = sB + w * 512;          // wave-uniform LDS dest (1KB/wave)

    for (int e = 0; e < E; ++e) {
        f32x4 acce[2];
        acce[0] = (f32x4){0.f, 0.f, 0.f, 0.f};
        acce[1] = (f32x4){0.f, 0.f, 0.f, 0.f};
        const bf16* Wbase = Wt + ((size_t)e * Ksteps * Mtot + col0) * 32;

        for (int ks = 0; ks < Ksteps; ++ks) {
            __syncthreads();                               // sB free (+ covers sA/sCo 1st iter)
            async_ld16(Wbase + (size_t)ks * Mtot * 32 + tid * 8, sBw);
            __syncthreads();                               // sB ready (vmcnt drained)
            const bf16x8 bfr = *(const bf16x8*)(sB + (16 * w + ml) * 32 + 8 * quad);
            #pragma unroll
            for (int rt = 0; rt < 2; ++rt) {
                const bf16x8 afr = *(const bf16x8*)(sA + (16 * rt + ml) * strideA + ks * 32 + 8 * quad);
                acce[rt] = __builtin_amdgcn_mfma_f32_16x16x32_bf16(afr, bfr, acce[rt], 0, 0, 0);
            }
        }
        const float bv = (gcol < M) ? bias[(size_t)e * M + gcol] : 0.f;
        #pragma unroll
        for (int rt = 0; rt < 2; ++rt)
            #pragma unroll
            for (int rg = 0; rg < 4; ++rg) {
                const float s = sCo[e * 32 + 16 * rt + 4 * quad + rg];
                acc[rt][rg] += s * (acce[rt][rg] + bv);
            }
    }

    if (gcol < M) {
        #pragma unroll
        for (int rt = 0; rt < 2; ++rt)
            #pragma unroll
            for (int rg = 0; rg < 4; ++rg) {
                const int gr = row0 + 16 * rt + 4 * quad + rg;
                float v = acc[rt][rg];
                if (act) v = (v > 0.f) ? v : (expf(v) - 1.f);
                if (Cf) Cf[(size_t)gr * ldc + gcol] = v;
                if (Cb) Cb[(size_t)gr * ldcb + gcol] = __float2bfloat16(v);
            }
    }
}

// ---------------------------------------------------------------------------
// z: read fused mu|lv [4096][64], write mu/lv f32 to d_out and z bf16 into
// the three concat buffers' [0,32) columns.
// ---------------------------------------------------------------------------
__global__ void z_kernel(const float* __restrict__ mulv, const float* __restrict__ eps,
                         float* __restrict__ out_mu, float* __restrict__ out_lv,
                         bf16* __restrict__ Azc, bf16* __restrict__ Azd1,
                         bf16* __restrict__ Azd2) {
    const int i = blockIdx.x * blockDim.x + threadIdx.x;
    if (i >= N_BATCH * LATENT) return;
    const int r = i >> 5, l = i & 31;
    const float m  = mulv[(size_t)r * 64 + l];
    const float lv = mulv[(size_t)r * 64 + 32 + l];
    out_mu[i] = m; out_lv[i] = lv;
    const bf16 v = __float2bfloat16(m + eps[i] * expf(0.5f * lv));
    Azc [(size_t)r * 320 + l] = v;
    Azd1[(size_t)r * 288 + l] = v;
    Azd2[(size_t)r * 288 + l] = v;
}

__global__ void softmax_kernel(float* __restrict__ co) {
    const int n = blockIdx.x * blockDim.x + threadIdx.x;
    if (n >= N_BATCH) return;
    float v[EXPERTS];
    float m = -1e30f;
    #pragma unroll
    for (int i = 0; i < EXPERTS; ++i) { v[i] = co[(size_t)n * EXPERTS + i]; m = fmaxf(m, v[i]); }
    float s = 0.f;
    #pragma unroll
    for (int i = 0; i < EXPERTS; ++i) { v[i] = expf(v[i] - m); s += v[i]; }
    const float inv = 1.f / s;
    #pragma unroll
    for (int i = 0; i < EXPERTS; ++i) co[(size_t)n * EXPERTS + i] = v[i] * inv;
}

// ---------------------------------------------------------------------------
extern "C" void kernel_launch(void* const* d_in, const int* in_sizes, int n_in,
                              void* d_out, int out_size, void* d_ws, size_t ws_size,
                              hipStream_t stream) {
    const float* x       = (const float*)d_in[0];
    const float* c       = (const float*)d_in[1];
    const float* eps     = (const float*)d_in[2];
    const float* enc_w1  = (const float*)d_in[3];
    const float* enc_b1  = (const float*)d_in[4];
    const float* enc_w2  = (const float*)d_in[5];
    const float* enc_b2  = (const float*)d_in[6];
    const float* enc_wmu = (const float*)d_in[7];
    const float* enc_bmu = (const float*)d_in[8];
    const float* enc_wlv = (const float*)d_in[9];
    const float* enc_blv = (const float*)d_in[10];
    const float* g_w0    = (const float*)d_in[11];
    const float* g_b0    = (const float*)d_in[12];
    const float* g_w1    = (const float*)d_in[13];
    const float* g_b1    = (const float*)d_in[14];
    const float* g_w2    = (const float*)d_in[15];
    const float* g_b2    = (const float*)d_in[16];
    const float* w0      = (const float*)d_in[17];
    const float* b0      = (const float*)d_in[18];
    const float* w1      = (const float*)d_in[19];
    const float* b1      = (const float*)d_in[20];
    const float* w2      = (const float*)d_in[21];
    const float* b2      = (const float*)d_in[22];

    // output (f32): [layer (4096x267) | mu (4096x32) | logvar (4096x32)]
    float* out_layer = (float*)d_out;
    float* out_mu    = out_layer + (size_t)N_BATCH * FRAME;
    float* out_lv    = out_mu    + (size_t)N_BATCH * LATENT;

    // ---- workspace layout (16B-aligned) ----
    char* p = (char*)d_ws;
    float* co      = (float*)p;  p += (size_t)N_BATCH * EXPERTS * 4;
    float* biasCat = (float*)p;  p += 64 * 4;
    float* mulv    = (float*)p;  p += (size_t)N_BATCH * 64 * 4;
    bf16* Axc   = (bf16*)p;      p += (size_t)N_BATCH * 544 * 2;
    bf16* Axh1  = (bf16*)p;      p += (size_t)N_BATCH * 544 * 2;
    bf16* Axh2  = (bf16*)p;      p += (size_t)N_BATCH * 544 * 2;
    bf16* Azc   = (bf16*)p;      p += (size_t)N_BATCH * 320 * 2;
    bf16* Azd1  = (bf16*)p;      p += (size_t)N_BATCH * 288 * 2;
    bf16* Azd2  = (bf16*)p;      p += (size_t)N_BATCH * 288 * 2;
    bf16* Bg1   = (bf16*)p;      p += (size_t)N_BATCH * 64 * 2;
    bf16* Bg2   = (bf16*)p;      p += (size_t)N_BATCH * 64 * 2;
    // repacked weights [E][Ksteps][Mtot][32]
    bf16* Wt_e1 = (bf16*)p;      p += (size_t)17 * 256 * 32 * 2;
    bf16* Wt_e2 = (bf16*)p;      p += (size_t)17 * 256 * 32 * 2;
    bf16* Wt_ml = (bf16*)p;      p += (size_t)17 * 64 * 32 * 2;
    bf16* Wt_g0 = (bf16*)p;      p += (size_t)10 * 64 * 32 * 2;
    bf16* Wt_g1 = (bf16*)p;      p += (size_t)2 * 64 * 32 * 2;
    bf16* Wt_g2 = (bf16*)p;      p += (size_t)2 * 64 * 32 * 2;
    bf16* Wt_w0 = (bf16*)p;      p += (size_t)EXPERTS * 10 * 256 * 32 * 2;
    bf16* Wt_w1 = (bf16*)p;      p += (size_t)EXPERTS * 9 * 256 * 32 * 2;
    bf16* Wt_w2 = (bf16*)p;      p += (size_t)EXPERTS * 9 * 320 * 32 * 2;

    const dim3 blk(256);

    // ---- stage 0: conversions ----
    cvt_kernel<<<dim3(3, N_BATCH), blk, 0, stream>>>(x, c, enc_bmu, enc_blv,
        Axc, Axh1, Axh2, Azc, biasCat);

    WTab tab;
    int cum = 0, n = 0;
    auto add = [&](const float* src, bf16* dst, int K, int M, int Mtot, int mOff, int E) {
        const int Ks = (K + 31) / 32 == 0 ? 1 : ((((K + 31) / 32) * 32 == 0) ? 1 : 0);
        (void)Ks;
        int Ksteps;
        if (K == 534 || K == 523) Ksteps = 17;
        else if (K == 299) Ksteps = 10;
        else if (K == 288) Ksteps = 9;
        else Ksteps = 2;   // K=64
        const int Mtiles = (M + 31) / 32;
        tab.e[n] = {src, dst, K, M, Mtot, mOff, Ksteps, Mtiles, cum};
        cum += E * Ksteps * Mtiles;
        ++n;
    };
    add(enc_w1,  Wt_e1, 534, 256, 256, 0, 1);
    add(enc_w2,  Wt_e2, 523, 256, 256, 0, 1);
    add(enc_wmu, Wt_ml, 523, 32, 64, 0, 1);
    add(enc_wlv, Wt_ml, 523, 32, 64, 32, 1);
    add(g_w0,    Wt_g0, 299, 64, 64, 0, 1);
    add(g_w1,    Wt_g1, 64, 64, 64, 0, 1);
    add(g_w2,    Wt_g2, 64, 6, 64, 0, 1);
    add(w0,      Wt_w0, 299, 256, 256, 0, EXPERTS);
    add(w1,      Wt_w1, 288, 256, 256, 0, EXPERTS);
    add(w2,      Wt_w2, 288, 267, 320, 0, EXPERTS);
    tab.total = cum;
    wtr_kernel<<<dim3(cum), blk, 0, stream>>>(tab);

    auto smem = [](int Kpad) { return (size_t)32 * (Kpad + 8) * 2 + 4096 + 768; };
    const int gy = N_BATCH / 32;   // 128 row-tiles

    // 1) h1 = elu([x|c] @ enc_w1 + b1) -> Axh1[:,267:523]
    gemm_moe<<<dim3(4, gy), blk, smem(544), stream>>>(Axc, 544, Wt_e1, enc_b1,
        nullptr, 1, 256, 256, nullptr, 0, Axh1 + FRAME, 544, 1);
    // 2) h2 = elu([x|h1] @ enc_w2 + b2) -> Axh2[:,267:523]
    gemm_moe<<<dim3(4, gy), blk, smem(544), stream>>>(Axh1, 544, Wt_e2, enc_b2,
        nullptr, 1, 256, 256, nullptr, 0, Axh2 + FRAME, 544, 1);
    // 3) mu|lv fused -> mulv ws (f32, ldc 64)
    gemm_moe<<<dim3(1, gy), blk, smem(544), stream>>>(Axh2, 544, Wt_ml, biasCat,
        nullptr, 1, 64, 64, mulv, 64, nullptr, 0, 0);
    // 4) z -> concat buffers; mu/lv -> d_out
    z_kernel<<<dim3((N_BATCH * LATENT + 255) / 256), blk, 0, stream>>>(
        mulv, eps, out_mu, out_lv, Azc, Azd1, Azd2);
    // 5) g1 = elu([z|c] @ g_w0 + b0) -> Bg1
    gemm_moe<<<dim3(1, gy), blk, smem(320), stream>>>(Azc, 320, Wt_g0, g_b0,
        nullptr, 1, 64, 64, nullptr, 0, Bg1, 64, 1);
    // 6) g2 = elu(g1 @ g_w1 + b1) -> Bg2
    gemm_moe<<<dim3(1, gy), blk, smem(64), stream>>>(Bg1, 64, Wt_g1, g_b1,
        nullptr, 1, 64, 64, nullptr, 0, Bg2, 64, 1);
    // 7) logits = g2 @ g_w2 + b2 -> co
    gemm_moe<<<dim3(1, gy), blk, smem(64), stream>>>(Bg2, 64, Wt_g2, g_b2,
        nullptr, 1, EXPERTS, 64, co, EXPERTS, nullptr, 0, 0);
    // 8) coeff = softmax(logits)
    softmax_kernel<<<dim3((N_BATCH + 255) / 256), blk, 0, stream>>>(co);
    // 9) dh1 = elu(moe([z|c], w0, b0)) -> Azd1[:,32:288]
    gemm_moe<<<dim3(4, gy), blk, smem(320), stream>>>(Azc, 320, Wt_w0, b0,
        co, EXPERTS, 256, 256, nullptr, 0, Azd1 + LATENT, 288, 1);
    // 10) dh2 = elu(moe([z|dh1], w1, b1)) -> Azd2[:,32:288]
    gemm_moe<<<dim3(4, gy), blk, smem(288), stream>>>(Azd1, 288, Wt_w1, b1,
        co, EXPERTS, 256, 256, nullptr, 0, Azd2 + LATENT, 288, 1);
    // 11) out = moe([z|dh2], w2, b2) -> d_out
    gemm_moe<<<dim3(5, gy), blk, smem(288), stream>>>(Azd2, 288, Wt_w2, b2,
        co, EXPERTS, FRAME, 320, out_layer, FRAME, nullptr, 0, 0);
}

// Round 7
// 237.986 us; speedup vs baseline: 5.0289x; 1.1087x over previous
//
#include <hip/hip_runtime.h>
#include <hip/hip_bf16.h>
#include <math.h>

// Problem constants (PoseMixtureVAE)
#define N_BATCH 4096
#define FRAME   267
#define LATENT  32
#define HIDDEN  256
#define GATE_H  64
#define EXPERTS 6
// Kpads: [x|c]=534->544 (17 ksteps), [x|h]=523->544 (17), [z|c]=299->320 (10),
//        [z|h]=288 (9), gate hidden 64 (2)

typedef __hip_bfloat16 bf16;
typedef __bf16  bf16x8 __attribute__((ext_vector_type(8)));
typedef float   f32x4  __attribute__((ext_vector_type(4)));

__device__ __forceinline__ float eluf(float v) {
    return (v > 0.f) ? v : (expf(v) - 1.f);
}

// ---------------------------------------------------------------------------
// cvt: build bf16 concat-activation buffers + concat bias for mu|lv GEMM.
//   Axc [4096][544] = [x | c | 0];  Axh1/Axh2 [4096][544]: x part + zero tail
//   Azc [4096][320]: cols 32..298 = c, 299..319 = 0 (cols 0..31 by mulv_z)
//   biasCat[64] = [enc_bmu | enc_blv]
// ---------------------------------------------------------------------------
__global__ void cvt_kernel(const float* __restrict__ x, const float* __restrict__ c,
                           const float* __restrict__ bmu, const float* __restrict__ blv,
                           bf16* __restrict__ Axc, bf16* __restrict__ Axh1,
                           bf16* __restrict__ Axh2, bf16* __restrict__ Azc,
                           float* __restrict__ biasCat) {
    const int col = blockIdx.x * blockDim.x + threadIdx.x;
    const int r   = blockIdx.y;
    if (blockIdx.x == 0 && r == 0 && threadIdx.x < 64)
        biasCat[threadIdx.x] = (threadIdx.x < 32) ? bmu[threadIdx.x] : blv[threadIdx.x - 32];
    if (col >= 544) return;
    const size_t o = (size_t)r * 544 + col;
    float vx = 0.f;
    if (col < FRAME)          vx = x[(size_t)r * FRAME + col];
    else if (col < 2 * FRAME) vx = c[(size_t)r * FRAME + col - FRAME];
    Axc[o] = __float2bfloat16(vx);
    if (col < FRAME) {
        bf16 v = __float2bfloat16(x[(size_t)r * FRAME + col]);
        Axh1[o] = v; Axh2[o] = v;
    } else if (col >= FRAME + HIDDEN) {
        bf16 zv = __float2bfloat16(0.f);
        Axh1[o] = zv; Axh2[o] = zv;
    }
    if (col >= 32 && col < 320) {
        float vc = (col < 32 + FRAME) ? c[(size_t)r * FRAME + col - 32] : 0.f;
        Azc[(size_t)r * 320 + col] = __float2bfloat16(vc);
    }
}

// ---------------------------------------------------------------------------
// Fused weight repack: src f32 [E][K][M] -> dst bf16 [E][Ksteps][Mtot][32]
// (k-block contiguous). Zero-pad k>=K and m in [M, Mtiles*32).
// ---------------------------------------------------------------------------
struct WEnt { const float* src; bf16* dst; int K, M, Mtot, mOff, Ksteps, Mtiles, cum; };
struct WTab { WEnt e[10]; int total; };

__global__ __launch_bounds__(256) void wtr_kernel(WTab tab) {
    __shared__ float tbuf[32][33];
    const int bid = blockIdx.x;
    int i = 0;
    while (i < 9 && bid >= tab.e[i + 1].cum) ++i;
    const WEnt en = tab.e[i];
    const int t    = bid - en.cum;
    const int perE = en.Ksteps * en.Mtiles;
    const int e    = t / perE;
    const int r    = t - e * perE;
    const int mt   = r / en.Ksteps;
    const int ks   = r - mt * en.Ksteps;

    const int tx = threadIdx.x & 31, ty = threadIdx.x >> 5;
    const float* src = en.src + (size_t)e * en.K * en.M;
    #pragma unroll
    for (int i0 = 0; i0 < 32; i0 += 8) {
        const int k = ks * 32 + i0 + ty, m = mt * 32 + tx;
        tbuf[i0 + ty][tx] = (k < en.K && m < en.M) ? src[(size_t)k * en.M + m] : 0.f;
    }
    __syncthreads();
    bf16* dst = en.dst + ((size_t)(e * en.Ksteps + ks) * en.Mtot + en.mOff + mt * 32) * 32;
    #pragma unroll
    for (int i0 = 0; i0 < 32; i0 += 8) {
        const int mm = i0 + ty;
        dst[(size_t)mm * 32 + tx] = __float2bfloat16(tbuf[tx][mm]);
    }
}

// ---------------------------------------------------------------------------
// Barrier-free MFMA GEMM (AITER-style): A full-K in LDS (one barrier), B
// streamed straight into registers (coalesced 1KB/wave dwordx4), k-loop fully
// unrolled via templates so loads pipeline with vmcnt(N) != 0.
//   C[n,m] = act( sum_e coeff[n,e] * (A[n,:] @ We + bias_e) )
//   Block = 32 rows x (tilesPB*16 cols), 4 waves; wave w: tiles w, w+4, ...
//   Wt: [E][KSTEPS][Mtot][32]. bias f32 [E][M]. coeff f32 [4096][6] or null.
// ---------------------------------------------------------------------------
template<int KSTEPS, int E>
__global__ __launch_bounds__(256) void gemm_t(
    const bf16* __restrict__ A,            // [4096][Kpad]
    const bf16* __restrict__ Wt,
    const float* __restrict__ bias,
    const float* __restrict__ coeff,
    int M, int Mtot, int tilesPB,
    float* __restrict__ Cf, int ldc,
    bf16* __restrict__ Cb, int ldcb, int act)
{
    constexpr int Kpad = KSTEPS * 32;
    constexpr int strideA = Kpad + 8;
    __shared__ bf16  sA[32 * strideA];
    __shared__ float sCo[E * 32];

    const int tid  = threadIdx.x;
    const int w    = tid >> 6, lane = tid & 63;
    const int ml   = lane & 15, quad = lane >> 4;
    const int row0 = blockIdx.y * 32;
    const int colbase = blockIdx.x * tilesPB * 16;

    for (int idx = tid; idx < 32 * E; idx += 256) {
        const int e = idx >> 5, r = idx & 31;
        sCo[e * 32 + r] = coeff ? coeff[(size_t)(row0 + r) * EXPERTS + e] : 1.f;
    }
    {   // stage A: 32 rows x Kpad
        const int r = tid >> 3, kt = (tid & 7) * 8;
        for (int kk = kt; kk < Kpad; kk += 64)
            *(float4*)(sA + r * strideA + kk) =
                *(const float4*)(A + (size_t)(row0 + r) * Kpad + kk);
    }
    __syncthreads();

    for (int ct = w; ct < tilesPB; ct += 4) {
        const int col = colbase + ct * 16 + ml;
        f32x4 acc0 = (f32x4){0.f, 0.f, 0.f, 0.f};
        f32x4 acc1 = (f32x4){0.f, 0.f, 0.f, 0.f};
        for (int e = 0; e < E; ++e) {
            f32x4 p0 = (f32x4){0.f, 0.f, 0.f, 0.f};
            f32x4 p1 = (f32x4){0.f, 0.f, 0.f, 0.f};
            const bf16* wp = Wt + ((size_t)e * KSTEPS * Mtot + col) * 32 + quad * 8;
            #pragma unroll
            for (int ks = 0; ks < KSTEPS; ++ks) {
                const bf16x8 b  = *(const bf16x8*)(wp + (size_t)ks * Mtot * 32);
                const bf16x8 a0 = *(const bf16x8*)(sA + ml * strideA + ks * 32 + quad * 8);
                const bf16x8 a1 = *(const bf16x8*)(sA + (16 + ml) * strideA + ks * 32 + quad * 8);
                p0 = __builtin_amdgcn_mfma_f32_16x16x32_bf16(a0, b, p0, 0, 0, 0);
                p1 = __builtin_amdgcn_mfma_f32_16x16x32_bf16(a1, b, p1, 0, 0, 0);
            }
            const float bv = (col < M) ? bias[(size_t)e * M + col] : 0.f;
            #pragma unroll
            for (int rg = 0; rg < 4; ++rg) {
                acc0[rg] += sCo[e * 32 + quad * 4 + rg]      * (p0[rg] + bv);
                acc1[rg] += sCo[e * 32 + 16 + quad * 4 + rg] * (p1[rg] + bv);
            }
        }
        if (col < M) {
            #pragma unroll
            for (int rg = 0; rg < 4; ++rg) {
                const int r0g = row0 + quad * 4 + rg;
                const int r1g = r0g + 16;
                float v0 = acc0[rg], v1 = acc1[rg];
                if (act) { v0 = eluf(v0); v1 = eluf(v1); }
                if (Cf) { Cf[(size_t)r0g * ldc + col] = v0; Cf[(size_t)r1g * ldc + col] = v1; }
                if (Cb) { Cb[(size_t)r0g * ldcb + col] = __float2bfloat16(v0);
                          Cb[(size_t)r1g * ldcb + col] = __float2bfloat16(v1); }
            }
        }
    }
}

// ---------------------------------------------------------------------------
// mu|lv GEMM (M=64 fused) + z in one kernel. Grid: 128 blocks x 32 rows.
//   z = mu + eps*exp(0.5*lv) -> bf16 cols [0,32) of Azc/Azd1/Azd2;
//   mu/lv -> d_out f32.
// ---------------------------------------------------------------------------
__global__ __launch_bounds__(256) void mulv_z_kernel(
    const bf16* __restrict__ Axh2, const bf16* __restrict__ Wt_ml,
    const float* __restrict__ biasCat, const float* __restrict__ eps,
    float* __restrict__ out_mu, float* __restrict__ out_lv,
    bf16* __restrict__ Azc, bf16* __restrict__ Azd1, bf16* __restrict__ Azd2)
{
    constexpr int Kpad = 544, strideA = 552;
    __shared__ bf16  sA[32 * strideA];
    __shared__ float sML[32 * 64];

    const int tid = threadIdx.x;
    const int w = tid >> 6, lane = tid & 63;
    const int ml = lane & 15, quad = lane >> 4;
    const int row0 = blockIdx.x * 32;

    {
        const int r = tid >> 3, kt = (tid & 7) * 8;
        for (int kk = kt; kk < Kpad; kk += 64)
            *(float4*)(sA + r * strideA + kk) =
                *(const float4*)(Axh2 + (size_t)(row0 + r) * Kpad + kk);
    }
    __syncthreads();

    {   // wave w computes cols 16w..16w+15 of mu|lv
        const int col = 16 * w + ml;
        f32x4 p0 = (f32x4){0.f, 0.f, 0.f, 0.f};
        f32x4 p1 = (f32x4){0.f, 0.f, 0.f, 0.f};
        const bf16* wp = Wt_ml + (size_t)col * 32 + quad * 8;
        #pragma unroll
        for (int ks = 0; ks < 17; ++ks) {
            const bf16x8 b  = *(const bf16x8*)(wp + (size_t)ks * 64 * 32);
            const bf16x8 a0 = *(const bf16x8*)(sA + ml * strideA + ks * 32 + quad * 8);
            const bf16x8 a1 = *(const bf16x8*)(sA + (16 + ml) * strideA + ks * 32 + quad * 8);
            p0 = __builtin_amdgcn_mfma_f32_16x16x32_bf16(a0, b, p0, 0, 0, 0);
            p1 = __builtin_amdgcn_mfma_f32_16x16x32_bf16(a1, b, p1, 0, 0, 0);
        }
        const float bv = biasCat[col];
        #pragma unroll
        for (int rg = 0; rg < 4; ++rg) {
            sML[(quad * 4 + rg) * 64 + col]        = p0[rg] + bv;
            sML[(16 + quad * 4 + rg) * 64 + col]   = p1[rg] + bv;
        }
    }
    __syncthreads();

    for (int i = tid; i < 32 * LATENT; i += 256) {
        const int r = i >> 5, l = i & 31;
        const float m  = sML[r * 64 + l];
        const float lv = sML[r * 64 + 32 + l];
        const int gi = (row0 + r) * LATENT + l;
        out_mu[gi] = m; out_lv[gi] = lv;
        const bf16 zb = __float2bfloat16(m + eps[gi] * expf(0.5f * lv));
        Azc [(size_t)(row0 + r) * 320 + l] = zb;
        Azd1[(size_t)(row0 + r) * 288 + l] = zb;
        Azd2[(size_t)(row0 + r) * 288 + l] = zb;
    }
}

// ---------------------------------------------------------------------------
// Fused gate: g1 = elu([z|c]@W0+b0), g2 = elu(g1@W1+b1), logits = g2@W2+b2,
// coeff = softmax(logits). All within a 32-row block. Grid: 128 blocks.
// ---------------------------------------------------------------------------
__global__ __launch_bounds__(256) void gate_kernel(
    const bf16* __restrict__ Azc,
    const bf16* __restrict__ Wg0, const bf16* __restrict__ Wg1,
    const bf16* __restrict__ Wg2,
    const float* __restrict__ gb0, const float* __restrict__ gb1,
    const float* __restrict__ gb2, float* __restrict__ co)
{
    constexpr int Kpad = 320, strideA = 328, strideG = 72;
    __shared__ bf16  sA[32 * strideA];
    __shared__ bf16  sG1[32 * strideG];
    __shared__ bf16  sG2[32 * strideG];
    __shared__ float sLg[32 * 16];

    const int tid = threadIdx.x;
    const int w = tid >> 6, lane = tid & 63;
    const int ml = lane & 15, quad = lane >> 4;
    const int row0 = blockIdx.x * 32;

    {
        const int r = tid >> 3, kt = (tid & 7) * 8;
        for (int kk = kt; kk < Kpad; kk += 64)
            *(float4*)(sA + r * strideA + kk) =
                *(const float4*)(Azc + (size_t)(row0 + r) * Kpad + kk);
    }
    __syncthreads();

    {   // g1: K=320(10), M=64
        const int col = 16 * w + ml;
        f32x4 p0 = (f32x4){0.f, 0.f, 0.f, 0.f};
        f32x4 p1 = (f32x4){0.f, 0.f, 0.f, 0.f};
        const bf16* wp = Wg0 + (size_t)col * 32 + quad * 8;
        #pragma unroll
        for (int ks = 0; ks < 10; ++ks) {
            const bf16x8 b  = *(const bf16x8*)(wp + (size_t)ks * 64 * 32);
            const bf16x8 a0 = *(const bf16x8*)(sA + ml * strideA + ks * 32 + quad * 8);
            const bf16x8 a1 = *(const bf16x8*)(sA + (16 + ml) * strideA + ks * 32 + quad * 8);
            p0 = __builtin_amdgcn_mfma_f32_16x16x32_bf16(a0, b, p0, 0, 0, 0);
            p1 = __builtin_amdgcn_mfma_f32_16x16x32_bf16(a1, b, p1, 0, 0, 0);
        }
        const float bv = gb0[col];
        #pragma unroll
        for (int rg = 0; rg < 4; ++rg) {
            sG1[(quad * 4 + rg) * strideG + col]      = __float2bfloat16(eluf(p0[rg] + bv));
            sG1[(16 + quad * 4 + rg) * strideG + col] = __float2bfloat16(eluf(p1[rg] + bv));
        }
    }
    __syncthreads();

    {   // g2: K=64(2), M=64
        const int col = 16 * w + ml;
        f32x4 p0 = (f32x4){0.f, 0.f, 0.f, 0.f};
        f32x4 p1 = (f32x4){0.f, 0.f, 0.f, 0.f};
        const bf16* wp = Wg1 + (size_t)col * 32 + quad * 8;
        #pragma unroll
        for (int ks = 0; ks < 2; ++ks) {
            const bf16x8 b  = *(const bf16x8*)(wp + (size_t)ks * 64 * 32);
            const bf16x8 a0 = *(const bf16x8*)(sG1 + ml * strideG + ks * 32 + quad * 8);
            const bf16x8 a1 = *(const bf16x8*)(sG1 + (16 + ml) * strideG + ks * 32 + quad * 8);
            p0 = __builtin_amdgcn_mfma_f32_16x16x32_bf16(a0, b, p0, 0, 0, 0);
            p1 = __builtin_amdgcn_mfma_f32_16x16x32_bf16(a1, b, p1, 0, 0, 0);
        }
        const float bv = gb1[col];
        #pragma unroll
        for (int rg = 0; rg < 4; ++rg) {
            sG2[(quad * 4 + rg) * strideG + col]      = __float2bfloat16(eluf(p0[rg] + bv));
            sG2[(16 + quad * 4 + rg) * strideG + col] = __float2bfloat16(eluf(p1[rg] + bv));
        }
    }
    __syncthreads();

    if (w == 0) {   // logits: K=64(2), M=6 (cols 0..15, Mtot=32)
        f32x4 p0 = (f32x4){0.f, 0.f, 0.f, 0.f};
        f32x4 p1 = (f32x4){0.f, 0.f, 0.f, 0.f};
        const bf16* wp = Wg2 + (size_t)ml * 32 + quad * 8;
        #pragma unroll
        for (int ks = 0; ks < 2; ++ks) {
            const bf16x8 b  = *(const bf16x8*)(wp + (size_t)ks * 32 * 32);
            const bf16x8 a0 = *(const bf16x8*)(sG2 + ml * strideG + ks * 32 + quad * 8);
            const bf16x8 a1 = *(const bf16x8*)(sG2 + (16 + ml) * strideG + ks * 32 + quad * 8);
            p0 = __builtin_amdgcn_mfma_f32_16x16x32_bf16(a0, b, p0, 0, 0, 0);
            p1 = __builtin_amdgcn_mfma_f32_16x16x32_bf16(a1, b, p1, 0, 0, 0);
        }
        const float bv = (ml < EXPERTS) ? gb2[ml] : 0.f;
        #pragma unroll
        for (int rg = 0; rg < 4; ++rg) {
            sLg[(quad * 4 + rg) * 16 + ml]      = p0[rg] + bv;
            sLg[(16 + quad * 4 + rg) * 16 + ml] = p1[rg] + bv;
        }
    }
    __syncthreads();

    if (tid < 32) {
        float v[EXPERTS];
        float m = -1e30f;
        #pragma unroll
        for (int i = 0; i < EXPERTS; ++i) { v[i] = sLg[tid * 16 + i]; m = fmaxf(m, v[i]); }
        float s = 0.f;
        #pragma unroll
        for (int i = 0; i < EXPERTS; ++i) { v[i] = expf(v[i] - m); s += v[i]; }
        const float inv = 1.f / s;
        #pragma unroll
        for (int i = 0; i < EXPERTS; ++i)
            co[(size_t)(row0 + tid) * EXPERTS + i] = v[i] * inv;
    }
}

// ---------------------------------------------------------------------------
extern "C" void kernel_launch(void* const* d_in, const int* in_sizes, int n_in,
                              void* d_out, int out_size, void* d_ws, size_t ws_size,
                              hipStream_t stream) {
    const float* x       = (const float*)d_in[0];
    const float* c       = (const float*)d_in[1];
    const float* eps     = (const float*)d_in[2];
    const float* enc_w1  = (const float*)d_in[3];
    const float* enc_b1  = (const float*)d_in[4];
    const float* enc_w2  = (const float*)d_in[5];
    const float* enc_b2  = (const float*)d_in[6];
    const float* enc_wmu = (const float*)d_in[7];
    const float* enc_bmu = (const float*)d_in[8];
    const float* enc_wlv = (const float*)d_in[9];
    const float* enc_blv = (const float*)d_in[10];
    const float* g_w0    = (const float*)d_in[11];
    const float* g_b0    = (const float*)d_in[12];
    const float* g_w1    = (const float*)d_in[13];
    const float* g_b1    = (const float*)d_in[14];
    const float* g_w2    = (const float*)d_in[15];
    const float* g_b2    = (const float*)d_in[16];
    const float* w0      = (const float*)d_in[17];
    const float* b0      = (const float*)d_in[18];
    const float* w1      = (const float*)d_in[19];
    const float* b1      = (const float*)d_in[20];
    const float* w2      = (const float*)d_in[21];
    const float* b2      = (const float*)d_in[22];

    // output (f32): [layer (4096x267) | mu (4096x32) | logvar (4096x32)]
    float* out_layer = (float*)d_out;
    float* out_mu    = out_layer + (size_t)N_BATCH * FRAME;
    float* out_lv    = out_mu    + (size_t)N_BATCH * LATENT;

    // ---- workspace layout (16B-aligned) ----
    char* p = (char*)d_ws;
    float* co      = (float*)p;  p += (size_t)N_BATCH * EXPERTS * 4;
    float* biasCat = (float*)p;  p += 64 * 4;
    bf16* Axc   = (bf16*)p;      p += (size_t)N_BATCH * 544 * 2;
    bf16* Axh1  = (bf16*)p;      p += (size_t)N_BATCH * 544 * 2;
    bf16* Axh2  = (bf16*)p;      p += (size_t)N_BATCH * 544 * 2;
    bf16* Azc   = (bf16*)p;      p += (size_t)N_BATCH * 320 * 2;
    bf16* Azd1  = (bf16*)p;      p += (size_t)N_BATCH * 288 * 2;
    bf16* Azd2  = (bf16*)p;      p += (size_t)N_BATCH * 288 * 2;
    // repacked weights [E][Ksteps][Mtot][32]
    bf16* Wt_e1 = (bf16*)p;      p += (size_t)17 * 256 * 32 * 2;
    bf16* Wt_e2 = (bf16*)p;      p += (size_t)17 * 256 * 32 * 2;
    bf16* Wt_ml = (bf16*)p;      p += (size_t)17 * 64 * 32 * 2;
    bf16* Wt_g0 = (bf16*)p;      p += (size_t)10 * 64 * 32 * 2;
    bf16* Wt_g1 = (bf16*)p;      p += (size_t)2 * 64 * 32 * 2;
    bf16* Wt_g2 = (bf16*)p;      p += (size_t)2 * 32 * 32 * 2;
    bf16* Wt_w0 = (bf16*)p;      p += (size_t)EXPERTS * 10 * 256 * 32 * 2;
    bf16* Wt_w1 = (bf16*)p;      p += (size_t)EXPERTS * 9 * 256 * 32 * 2;
    bf16* Wt_w2 = (bf16*)p;      p += (size_t)EXPERTS * 9 * 320 * 32 * 2;

    const dim3 blk(256);

    // ---- conversions ----
    cvt_kernel<<<dim3(3, N_BATCH), blk, 0, stream>>>(x, c, enc_bmu, enc_blv,
        Axc, Axh1, Axh2, Azc, biasCat);

    WTab tab;
    int cum = 0, n = 0;
    auto add = [&](const float* src, bf16* dst, int K, int M, int Mtot, int mOff, int E) {
        int Ksteps;
        if (K == 534 || K == 523) Ksteps = 17;
        else if (K == 299) Ksteps = 10;
        else if (K == 288) Ksteps = 9;
        else Ksteps = 2;   // K=64
        const int Mtiles = (M + 31) / 32;
        tab.e[n] = {src, dst, K, M, Mtot, mOff, Ksteps, Mtiles, cum};
        cum += E * Ksteps * Mtiles;
        ++n;
    };
    add(enc_w1,  Wt_e1, 534, 256, 256, 0, 1);
    add(enc_w2,  Wt_e2, 523, 256, 256, 0, 1);
    add(enc_wmu, Wt_ml, 523, 32, 64, 0, 1);
    add(enc_wlv, Wt_ml, 523, 32, 64, 32, 1);
    add(g_w0,    Wt_g0, 299, 64, 64, 0, 1);
    add(g_w1,    Wt_g1, 64, 64, 64, 0, 1);
    add(g_w2,    Wt_g2, 64, 6, 32, 0, 1);
    add(w0,      Wt_w0, 299, 256, 256, 0, EXPERTS);
    add(w1,      Wt_w1, 288, 256, 256, 0, EXPERTS);
    add(w2,      Wt_w2, 288, 267, 320, 0, EXPERTS);
    tab.total = cum;
    wtr_kernel<<<dim3(cum), blk, 0, stream>>>(tab);

    const int gy = N_BATCH / 32;   // 128 row-tiles

    // 1) h1 = elu([x|c] @ enc_w1 + b1) -> Axh1[:,267:523]
    gemm_t<17, 1><<<dim3(2, gy), blk, 0, stream>>>(Axc, Wt_e1, enc_b1,
        nullptr, 256, 256, 8, nullptr, 0, Axh1 + FRAME, 544, 1);
    // 2) h2 = elu([x|h1] @ enc_w2 + b2) -> Axh2[:,267:523]
    gemm_t<17, 1><<<dim3(2, gy), blk, 0, stream>>>(Axh1, Wt_e2, enc_b2,
        nullptr, 256, 256, 8, nullptr, 0, Axh2 + FRAME, 544, 1);
    // 3) mu|lv + z (fused)
    mulv_z_kernel<<<dim3(gy), blk, 0, stream>>>(Axh2, Wt_ml, biasCat, eps,
        out_mu, out_lv, Azc, Azd1, Azd2);
    // 4) gate chain + softmax (fused)
    gate_kernel<<<dim3(gy), blk, 0, stream>>>(Azc, Wt_g0, Wt_g1, Wt_g2,
        g_b0, g_b1, g_b2, co);
    // 5) dh1 = elu(moe([z|c], w0, b0)) -> Azd1[:,32:288]
    gemm_t<10, EXPERTS><<<dim3(2, gy), blk, 0, stream>>>(Azc, Wt_w0, b0,
        co, 256, 256, 8, nullptr, 0, Azd1 + LATENT, 288, 1);
    // 6) dh2 = elu(moe([z|dh1], w1, b1)) -> Azd2[:,32:288]
    gemm_t<9, EXPERTS><<<dim3(2, gy), blk, 0, stream>>>(Azd1, Wt_w1, b1,
        co, 256, 256, 8, nullptr, 0, Azd2 + LATENT, 288, 1);
    // 7) out = moe([z|dh2], w2, b2) -> d_out
    gemm_t<9, EXPERTS><<<dim3(2, gy), blk, 0, stream>>>(Azd2, Wt_w2, b2,
        co, FRAME, 320, 10, out_layer, FRAME, nullptr, 0, 0);
}